// Round 1
// baseline (28254.266 us; speedup 1.0000x reference)
//
#include <hip/hip_runtime.h>
#include <math.h>

#define EMB   256
#define TWOE  512
#define NINIT 1024
#define NSTEP 512
#define NPS   256
#define TOTAL (NINIT + NSTEP * NPS)   // 132096
#define MM    65536

// ---- workspace layout (bytes) ----
#define OFF_VEC 0
#define OFF_H   (TOTAL * EMB * 4)            // 135266304
#define OFF_VAL (OFF_H + NPS * EMB * 4)      // +262144
#define OFF_CNT (OFF_VAL + MM * 4)           // +262144
#define OFF_ACC (OFF_CNT + 256)
#define OFF_PW  (OFF_ACC + 256)

// acc layout: [0]=sum(pos) [1]=sum(neg) [2]=loss [3]=posOK [4]=negOK

__device__ __forceinline__ void grid_barrier(unsigned* cnt, unsigned nblk) {
  __syncthreads();
  if (threadIdx.x == 0) {
    __threadfence();  // release: make our global writes visible device-wide
    unsigned g = __hip_atomic_fetch_add(cnt, 1u, __ATOMIC_ACQ_REL, __HIP_MEMORY_SCOPE_AGENT);
    unsigned tgt = (g / nblk + 1u) * nblk;
    while (__hip_atomic_load(cnt, __ATOMIC_ACQUIRE, __HIP_MEMORY_SCOPE_AGENT) < tgt) {
      __builtin_amdgcn_s_sleep(2);
    }
    __threadfence();  // acquire: invalidate caches before reading others' writes
  }
  __syncthreads();
}

__global__ void zero_scratch(unsigned* cnt, double* acc) {
  if (threadIdx.x == 0) *cnt = 0u;
  if (threadIdx.x < 8) acc[threadIdx.x] = 0.0;
}

__global__ void init_copy(const float* __restrict__ src, float* __restrict__ dst) {
  int i = blockIdx.x * blockDim.x + threadIdx.x;  // 65536 float4 = 1024*256 floats
  reinterpret_cast<float4*>(dst)[i] = reinterpret_cast<const float4*>(src)[i];
}

// Persistent scan kernel: 256 blocks (1 per CU), 256 threads.
// Each step: phase1 h = relu(p @ W1[r] + b1[r]) into hbuf, barrier,
//            phase2 out = h @ W2[r] + b2[r] scattered into vec, barrier.
// Block (bi,bj) owns the 16x16 output tile (rows bi*16.., cols bj*16..).
__global__ __launch_bounds__(256, 1)
void scan_kernel(const float* __restrict__ W1, const float* __restrict__ b1,
                 const float* __restrict__ W2, const float* __restrict__ b2,
                 const int* __restrict__ inds, const int* __restrict__ pars,
                 const int* __restrict__ rules,
                 float* __restrict__ vec, float* __restrict__ hbuf,
                 unsigned* __restrict__ cnt)
{
  __shared__ float pL[16][TWOE];    // 32 KB: 16 gathered rows (concat of 2 parents)
  __shared__ float wT[16][516];     // ~33 KB: W tile transposed, padded (516*4B, 16B-aligned)
  const int tid = threadIdx.x;
  const int bi = blockIdx.x >> 4;
  const int bj = blockIdx.x & 15;
  const int ti = tid >> 4;
  const int tj = tid & 15;
  const int c0 = bj * 16;
  const unsigned nblk = gridDim.x;

  for (int s = 0; s < NSTEP; ++s) {
    const int r = rules[s];
    const float* __restrict__ W1r = W1 + (size_t)r * TWOE * EMB;
    const float* __restrict__ W2r = W2 + (size_t)r * EMB * EMB;

    // ---- stage p: gather 16 rows x 512 floats (2 parents each) ----
    for (int idx = tid; idx < 16 * 128; idx += 256) {
      int row = idx >> 7, c4 = idx & 127;
      int par = pars[(size_t)(s * NPS + bi * 16 + row) * 2 + (c4 >> 6)];
      float4 v = reinterpret_cast<const float4*>(vec + (size_t)par * EMB)[c4 & 63];
      reinterpret_cast<float4*>(&pL[row][0])[c4] = v;
    }
    // ---- stage W1 column-tile, transposed: wT[c][k] = W1r[k][c0+c] ----
    for (int idx = tid; idx < TWOE * 16; idx += 256) {
      int k = idx >> 4, c = idx & 15;
      wT[c][k] = W1r[(size_t)k * EMB + c0 + c];
    }
    __syncthreads();
    // ---- phase 1 compute: h[ti][tj] ----
    {
      const float4* p4 = reinterpret_cast<const float4*>(&pL[ti][0]);
      const float4* w4 = reinterpret_cast<const float4*>(&wT[tj][0]);
      float sx = 0.f, sy = 0.f, sz = 0.f, sw = 0.f;
      #pragma unroll 8
      for (int k4 = 0; k4 < TWOE / 4; ++k4) {
        float4 a = p4[k4], w = w4[k4];
        sx += a.x * w.x; sy += a.y * w.y; sz += a.z * w.z; sw += a.w * w.w;
      }
      float h = b1[r * EMB + c0 + tj] + ((sx + sy) + (sz + sw));
      hbuf[(size_t)(bi * 16 + ti) * EMB + c0 + tj] = fmaxf(h, 0.f);
    }
    grid_barrier(cnt, nblk);
    // ---- stage h rows (16 x 256) + W2 tile ----
    for (int idx = tid; idx < 16 * 64; idx += 256) {
      int row = idx >> 6, c4 = idx & 63;
      reinterpret_cast<float4*>(&pL[row][0])[c4] =
          reinterpret_cast<const float4*>(hbuf + (size_t)(bi * 16 + row) * EMB)[c4];
    }
    for (int idx = tid; idx < EMB * 16; idx += 256) {
      int k = idx >> 4, c = idx & 15;
      wT[c][k] = W2r[(size_t)k * EMB + c0 + c];
    }
    __syncthreads();
    // ---- phase 2 compute + scatter ----
    {
      const float4* p4 = reinterpret_cast<const float4*>(&pL[ti][0]);
      const float4* w4 = reinterpret_cast<const float4*>(&wT[tj][0]);
      float sx = 0.f, sy = 0.f, sz = 0.f, sw = 0.f;
      #pragma unroll 8
      for (int k4 = 0; k4 < EMB / 4; ++k4) {
        float4 a = p4[k4], w = w4[k4];
        sx += a.x * w.x; sy += a.y * w.y; sz += a.z * w.z; sw += a.w * w.w;
      }
      float o = b2[r * EMB + c0 + tj] + ((sx + sy) + (sz + sw));
      int orow = inds[s * NPS + bi * 16 + ti];
      vec[(size_t)orow * EMB + c0 + tj] = o;
    }
    grid_barrier(cnt, nblk);
  }
}

__global__ void reduce_pn(const float* __restrict__ pos, const float* __restrict__ neg,
                          double* acc) {
  double sp = 0.0, sn = 0.0;
  for (int m = blockIdx.x * blockDim.x + threadIdx.x; m < MM; m += gridDim.x * blockDim.x) {
    sp += (double)pos[m]; sn += (double)neg[m];
  }
  for (int o = 32; o; o >>= 1) { sp += __shfl_down(sp, o); sn += __shfl_down(sn, o); }
  __shared__ double rp[4], rn[4];
  int wid = threadIdx.x >> 6, lane = threadIdx.x & 63;
  if (lane == 0) { rp[wid] = sp; rn[wid] = sn; }
  __syncthreads();
  if (threadIdx.x == 0) {
    double tp = 0.0, tn = 0.0;
    for (int w = 0; w < 4; ++w) { tp += rp[w]; tn += rn[w]; }
    atomicAdd(&acc[0], tp); atomicAdd(&acc[1], tn);
  }
}

__global__ void pw_kernel(const double* __restrict__ acc, float* __restrict__ pw) {
  pw[0] = (float)(acc[1] / fmax(acc[0], 1.0));
}

// eval: block handles 64 masked rows; thread (a=tid>>4, b=tid&15) owns
// rows a*4..a*4+4 and h-columns b*16..b*16+16. e is chunked by 32 through LDS.
__global__ __launch_bounds__(256)
void eval_kernel(const float* __restrict__ vec, const int* __restrict__ mask,
                 const float* __restrict__ eW1, const float* __restrict__ eb1,
                 const float* __restrict__ eW2, const float* __restrict__ eb2,
                 float* __restrict__ val)
{
  __shared__ float xL[64][36];    // 64 rows x 32-e chunk (+pad)
  __shared__ float wL[32][260];   // 32 e x 256 k (+pad)
  __shared__ int mrow[64];
  const int tid = threadIdx.x;
  const int a = tid >> 4, b = tid & 15;
  const int m0 = blockIdx.x * 64;
  if (tid < 64) mrow[tid] = mask[m0 + tid];
  __syncthreads();

  float acc[4][16];
  #pragma unroll
  for (int i = 0; i < 4; ++i)
    #pragma unroll
    for (int j = 0; j < 16; ++j) acc[i][j] = 0.f;

  for (int c = 0; c < 8; ++c) {
    const int e0 = c * 32;
    for (int idx = tid; idx < 64 * 8; idx += 256) {
      int rr = idx >> 3, e4 = idx & 7;
      float4 v = reinterpret_cast<const float4*>(vec + (size_t)mrow[rr] * EMB + e0)[e4];
      reinterpret_cast<float4*>(&xL[rr][0])[e4] = v;
    }
    for (int idx = tid; idx < 32 * 64; idx += 256) {
      int e = idx >> 6, k4 = idx & 63;
      reinterpret_cast<float4*>(&wL[e][0])[k4] =
          reinterpret_cast<const float4*>(eW1 + (size_t)(e0 + e) * EMB)[k4];
    }
    __syncthreads();
    #pragma unroll 4
    for (int e = 0; e < 32; ++e) {
      float xs[4];
      #pragma unroll
      for (int rr = 0; rr < 4; ++rr) xs[rr] = xL[a * 4 + rr][e];
      const float4* wr = reinterpret_cast<const float4*>(&wL[e][0]) + b * 4;
      float wk[16];
      *reinterpret_cast<float4*>(&wk[0])  = wr[0];
      *reinterpret_cast<float4*>(&wk[4])  = wr[1];
      *reinterpret_cast<float4*>(&wk[8])  = wr[2];
      *reinterpret_cast<float4*>(&wk[12]) = wr[3];
      #pragma unroll
      for (int rr = 0; rr < 4; ++rr)
        #pragma unroll
        for (int kk = 0; kk < 16; ++kk)
          acc[rr][kk] = fmaf(xs[rr], wk[kk], acc[rr][kk]);
    }
    __syncthreads();
  }

  // epilogue: relu + eW2-weighted sum over this thread's 16 k, reduce over b
  float eb2v = eb2[0];
  float pv[4];
  #pragma unroll
  for (int rr = 0; rr < 4; ++rr) {
    float s = 0.f;
    #pragma unroll
    for (int kk = 0; kk < 16; ++kk) {
      float h = acc[rr][kk] + eb1[b * 16 + kk];
      h = fmaxf(h, 0.f);
      s += h * eW2[b * 16 + kk];
    }
    pv[rr] = s;
  }
  #pragma unroll
  for (int m = 1; m < 16; m <<= 1) {
    #pragma unroll
    for (int rr = 0; rr < 4; ++rr) pv[rr] += __shfl_xor(pv[rr], m);
  }
  if (b == 0) {
    #pragma unroll
    for (int rr = 0; rr < 4; ++rr) val[m0 + a * 4 + rr] = pv[rr] + eb2v;
  }
}

__global__ void loss_kernel(const float* __restrict__ val, const float* __restrict__ pos,
                            const float* __restrict__ neg, const float* __restrict__ tgt,
                            const float* __restrict__ pwp, double* acc)
{
  const float pw = pwp[0];
  double l = 0.0, pk = 0.0, nk = 0.0;
  for (int m = blockIdx.x * blockDim.x + threadIdx.x; m < MM; m += gridDim.x * blockDim.x) {
    float v = val[m], p = pos[m], n = neg[m], t = tgt[m];
    float lp = log1pf(expf(-fabsf(v)));
    float spn = fmaxf(-v, 0.f) + lp;   // softplus(-v)
    float spp = fmaxf(v, 0.f) + lp;    // softplus(v)
    float contrib = pw * t * spn + (1.f - t) * spp;
    l += (double)((p + n) * contrib);
    if (v >= 0.f) pk += (double)p; else nk += (double)n;
  }
  for (int o = 32; o; o >>= 1) {
    l += __shfl_down(l, o); pk += __shfl_down(pk, o); nk += __shfl_down(nk, o);
  }
  __shared__ double s0[4], s1[4], s2[4];
  int wid = threadIdx.x >> 6, lane = threadIdx.x & 63;
  if (lane == 0) { s0[wid] = l; s1[wid] = pk; s2[wid] = nk; }
  __syncthreads();
  if (threadIdx.x == 0) {
    double ta = 0.0, tb = 0.0, tc = 0.0;
    for (int w = 0; w < 4; ++w) { ta += s0[w]; tb += s1[w]; tc += s2[w]; }
    atomicAdd(&acc[2], ta); atomicAdd(&acc[3], tb); atomicAdd(&acc[4], tc);
  }
}

__global__ void writeout(const double* __restrict__ acc, float* __restrict__ out) {
  if (threadIdx.x == 0) {
    out[0] = (float)acc[2];
    out[1] = (float)acc[3];
    out[2] = (float)acc[4];
  }
}

extern "C" void kernel_launch(void* const* d_in, const int* in_sizes, int n_in,
                              void* d_out, int out_size, void* d_ws, size_t ws_size,
                              hipStream_t stream)
{
  (void)in_sizes; (void)n_in; (void)out_size; (void)ws_size;
  const float* init_vecs = (const float*)d_in[0];
  const float* W1  = (const float*)d_in[1];
  const float* b1  = (const float*)d_in[2];
  const float* W2  = (const float*)d_in[3];
  const float* b2  = (const float*)d_in[4];
  const float* eW1 = (const float*)d_in[5];
  const float* eb1 = (const float*)d_in[6];
  const float* eW2 = (const float*)d_in[7];
  const float* eb2 = (const float*)d_in[8];
  const float* pos = (const float*)d_in[9];
  const float* neg = (const float*)d_in[10];
  const float* tgt = (const float*)d_in[11];
  const int* inds  = (const int*)d_in[12];
  const int* pars  = (const int*)d_in[13];
  const int* rules = (const int*)d_in[14];
  const int* mask  = (const int*)d_in[15];

  char* ws = (char*)d_ws;
  float*    vec  = (float*)(ws + OFF_VEC);
  float*    hbuf = (float*)(ws + OFF_H);
  float*    val  = (float*)(ws + OFF_VAL);
  unsigned* cnt  = (unsigned*)(ws + OFF_CNT);
  double*   acc  = (double*)(ws + OFF_ACC);
  float*    pw   = (float*)(ws + OFF_PW);

  zero_scratch<<<1, 64, 0, stream>>>(cnt, acc);
  init_copy<<<256, 256, 0, stream>>>(init_vecs, vec);
  scan_kernel<<<256, 256, 0, stream>>>(W1, b1, W2, b2, inds, pars, rules, vec, hbuf, cnt);
  reduce_pn<<<128, 256, 0, stream>>>(pos, neg, acc);
  pw_kernel<<<1, 1, 0, stream>>>(acc, pw);
  eval_kernel<<<1024, 256, 0, stream>>>(vec, mask, eW1, eb1, eW2, eb2, val);
  loss_kernel<<<128, 256, 0, stream>>>(val, pos, neg, tgt, pw, acc);
  writeout<<<1, 1, 0, stream>>>(acc, (float*)d_out);
}

// Round 3
// 9433.070 us; speedup vs baseline: 2.9952x; 2.9952x over previous
//
#include <hip/hip_runtime.h>
#include <math.h>

#define EMB   256
#define TWOE  512
#define NINIT 1024
#define NSTEP 512
#define NPS   256
#define TOTAL (NINIT + NSTEP * NPS)   // 132096
#define MM    65536

// ---- workspace layout (bytes) ----
#define OFF_VEC 0
#define OFF_H   (TOTAL * EMB * 4)            // 135266304
#define OFF_VAL (OFF_H + NPS * EMB * 4)
#define OFF_CNT (OFF_VAL + MM * 4)
#define OFF_ACC (OFF_CNT + 4096)
#define OFF_PW  (OFF_ACC + 64)

// acc layout: [0]=sum(pos) [1]=sum(neg) [2]=loss [3]=posOK [4]=negOK

// ---- device-coherent (bypass L1/L2, served at coherence point) ops ----
__device__ __forceinline__ void store_dev_f32(float* p, float v) {
  asm volatile("global_store_dword %0, %1, off sc0 sc1" :: "v"(p), "v"(v) : "memory");
}
__device__ __forceinline__ float4 load_dev_f128(const float4* p) {
  float4 r;
  asm volatile("global_load_dwordx4 %0, %1, off sc0 sc1" : "=v"(r) : "v"(p));
  return r;
}

// barrier over n blocks sharing counter c. NO cache-invalidating fences:
// all cross-block data moves via sc0sc1 (coherence-point) ops, and vec rows
// are write-once so normal cached gathers can never observe staleness.
__device__ __forceinline__ void gbar(unsigned* c, unsigned n) {
  asm volatile("s_waitcnt vmcnt(0)" ::: "memory");  // drain our sc0sc1 stores
  __syncthreads();
  if (threadIdx.x == 0) {
    unsigned g = __hip_atomic_fetch_add(c, 1u, __ATOMIC_RELAXED, __HIP_MEMORY_SCOPE_AGENT);
    unsigned tgt = (g / n + 1u) * n;
    while (__hip_atomic_load(c, __ATOMIC_RELAXED, __HIP_MEMORY_SCOPE_AGENT) < tgt)
      __builtin_amdgcn_s_sleep(2);
  }
  __syncthreads();         // also a compiler memory barrier: post-loads can't hoist
}

__global__ void zero_scratch(unsigned* cnt, double* acc) {
  for (int i = threadIdx.x; i < 1024; i += 256) cnt[i] = 0u;
  if (threadIdx.x < 8) acc[threadIdx.x] = 0.0;
}

__global__ void init_copy(const float* __restrict__ src, float* __restrict__ dst) {
  int i = blockIdx.x * blockDim.x + threadIdx.x;
  reinterpret_cast<float4*>(dst)[i] = reinterpret_cast<const float4*>(src)[i];
}

// Persistent scan: 256 blocks x 256 threads; block (bi,bj) owns 16x16 out tile.
// phase1: h = relu(p @ W1[r] + b1[r]) -> hbuf (sc0sc1), 16-block group barrier
// phase2: out = h @ W2[r] + b2[r]     -> vec  (sc0sc1), full barrier
__global__ __launch_bounds__(256, 1)
void scan_kernel(const float* __restrict__ W1, const float* __restrict__ b1,
                 const float* __restrict__ W2, const float* __restrict__ b2,
                 const int* __restrict__ inds, const int* __restrict__ pars,
                 const int* __restrict__ rules,
                 float* __restrict__ vec, float* __restrict__ hbuf,
                 unsigned* __restrict__ cntbase)
{
  __shared__ float pL[16][516];     // padded: stride 516 -> ti banks distinct
  __shared__ float wT[16][516];
  const int tid = threadIdx.x;
  const int bi = blockIdx.x >> 4;
  const int bj = blockIdx.x & 15;
  const int ti = tid >> 4;
  const int tj = tid & 15;
  const int c0 = bj * 16;
  unsigned* cnt_full = cntbase;                    // offset 0
  unsigned* cnt_grp  = cntbase + 32 * (1 + bi);    // 128B-spaced per-group counters

  for (int s = 0; s < NSTEP; ++s) {
    const int r = rules[s];
    const float* __restrict__ W1r = W1 + (size_t)r * TWOE * EMB;
    const float* __restrict__ W2r = W2 + (size_t)r * EMB * EMB;

    // ---- stage p: gather 16 rows x 512 floats (normal cached loads: rows
    //      are write-once, any cached copy is necessarily fresh) ----
    for (int idx = tid; idx < 16 * 128; idx += 256) {
      int row = idx >> 7, c4 = idx & 127;
      int par = pars[(size_t)(s * NPS + bi * 16 + row) * 2 + (c4 >> 6)];
      float4 v = reinterpret_cast<const float4*>(vec + (size_t)par * EMB)[c4 & 63];
      reinterpret_cast<float4*>(&pL[row][0])[c4] = v;
    }
    // ---- stage W1 column-tile transposed via float4 (L2-cached, never inval) ----
    for (int idx = tid; idx < TWOE * 4; idx += 256) {
      int k = idx >> 2, cq = idx & 3;
      float4 w = *reinterpret_cast<const float4*>(W1r + (size_t)k * EMB + c0 + cq * 4);
      wT[cq * 4 + 0][k] = w.x; wT[cq * 4 + 1][k] = w.y;
      wT[cq * 4 + 2][k] = w.z; wT[cq * 4 + 3][k] = w.w;
    }
    __syncthreads();
    // ---- phase 1 compute ----
    {
      const float4* p4 = reinterpret_cast<const float4*>(&pL[ti][0]);
      const float4* w4 = reinterpret_cast<const float4*>(&wT[tj][0]);
      float sx = 0.f, sy = 0.f, sz = 0.f, sw = 0.f;
      #pragma unroll 8
      for (int k4 = 0; k4 < TWOE / 4; ++k4) {
        float4 a = p4[k4], w = w4[k4];
        sx += a.x * w.x; sy += a.y * w.y; sz += a.z * w.z; sw += a.w * w.w;
      }
      float h = b1[r * EMB + c0 + tj] + ((sx + sy) + (sz + sw));
      store_dev_f32(hbuf + (size_t)(bi * 16 + ti) * EMB + c0 + tj, fmaxf(h, 0.f));
    }
    gbar(cnt_grp, 16);   // only the 16 blocks sharing bi produce/consume h rows
    // ---- stage h rows (sc0sc1 loads: hbuf is rewritten every step) ----
    {
      const int i0 = tid, i1 = tid + 256, i2 = tid + 512, i3 = tid + 768;
      const float4* hb = reinterpret_cast<const float4*>(hbuf + (size_t)bi * 16 * EMB);
      float4 h0 = load_dev_f128(hb + i0);
      float4 h1 = load_dev_f128(hb + i1);
      float4 h2 = load_dev_f128(hb + i2);
      float4 h3 = load_dev_f128(hb + i3);
      asm volatile("s_waitcnt vmcnt(0)" ::: "memory");
      __builtin_amdgcn_sched_barrier(0);
      reinterpret_cast<float4*>(&pL[i0 >> 6][0])[i0 & 63] = h0;
      reinterpret_cast<float4*>(&pL[i1 >> 6][0])[i1 & 63] = h1;
      reinterpret_cast<float4*>(&pL[i2 >> 6][0])[i2 & 63] = h2;
      reinterpret_cast<float4*>(&pL[i3 >> 6][0])[i3 & 63] = h3;
    }
    for (int idx = tid; idx < EMB * 4; idx += 256) {
      int k = idx >> 2, cq = idx & 3;
      float4 w = *reinterpret_cast<const float4*>(W2r + (size_t)k * EMB + c0 + cq * 4);
      wT[cq * 4 + 0][k] = w.x; wT[cq * 4 + 1][k] = w.y;
      wT[cq * 4 + 2][k] = w.z; wT[cq * 4 + 3][k] = w.w;
    }
    __syncthreads();
    // ---- phase 2 compute + scatter ----
    {
      const float4* p4 = reinterpret_cast<const float4*>(&pL[ti][0]);
      const float4* w4 = reinterpret_cast<const float4*>(&wT[tj][0]);
      float sx = 0.f, sy = 0.f, sz = 0.f, sw = 0.f;
      #pragma unroll 8
      for (int k4 = 0; k4 < EMB / 4; ++k4) {
        float4 a = p4[k4], w = w4[k4];
        sx += a.x * w.x; sy += a.y * w.y; sz += a.z * w.z; sw += a.w * w.w;
      }
      float o = b2[r * EMB + c0 + tj] + ((sx + sy) + (sz + sw));
      int orow = inds[s * NPS + bi * 16 + ti];
      store_dev_f32(vec + (size_t)orow * EMB + c0 + tj, o);
    }
    gbar(cnt_full, 256);
  }
}

__global__ void reduce_pn(const float* __restrict__ pos, const float* __restrict__ neg,
                          double* acc) {
  double sp = 0.0, sn = 0.0;
  for (int m = blockIdx.x * blockDim.x + threadIdx.x; m < MM; m += gridDim.x * blockDim.x) {
    sp += (double)pos[m]; sn += (double)neg[m];
  }
  for (int o = 32; o; o >>= 1) { sp += __shfl_down(sp, o); sn += __shfl_down(sn, o); }
  __shared__ double rp[4], rn[4];
  int wid = threadIdx.x >> 6, lane = threadIdx.x & 63;
  if (lane == 0) { rp[wid] = sp; rn[wid] = sn; }
  __syncthreads();
  if (threadIdx.x == 0) {
    double tp = 0.0, tn = 0.0;
    for (int w = 0; w < 4; ++w) { tp += rp[w]; tn += rn[w]; }
    atomicAdd(&acc[0], tp); atomicAdd(&acc[1], tn);
  }
}

__global__ void pw_kernel(const double* __restrict__ acc, float* __restrict__ pw) {
  pw[0] = (float)(acc[1] / fmax(acc[0], 1.0));
}

__global__ __launch_bounds__(256)
void eval_kernel(const float* __restrict__ vec, const int* __restrict__ mask,
                 const float* __restrict__ eW1, const float* __restrict__ eb1,
                 const float* __restrict__ eW2, const float* __restrict__ eb2,
                 float* __restrict__ val)
{
  __shared__ float xL[64][36];
  __shared__ float wL[32][260];
  __shared__ int mrow[64];
  const int tid = threadIdx.x;
  const int a = tid >> 4, b = tid & 15;
  const int m0 = blockIdx.x * 64;
  if (tid < 64) mrow[tid] = mask[m0 + tid];
  __syncthreads();

  float acc[4][16];
  #pragma unroll
  for (int i = 0; i < 4; ++i)
    #pragma unroll
    for (int j = 0; j < 16; ++j) acc[i][j] = 0.f;

  for (int c = 0; c < 8; ++c) {
    const int e0 = c * 32;
    for (int idx = tid; idx < 64 * 8; idx += 256) {
      int rr = idx >> 3, e4 = idx & 7;
      float4 v = reinterpret_cast<const float4*>(vec + (size_t)mrow[rr] * EMB + e0)[e4];
      reinterpret_cast<float4*>(&xL[rr][0])[e4] = v;
    }
    for (int idx = tid; idx < 32 * 64; idx += 256) {
      int e = idx >> 6, k4 = idx & 63;
      reinterpret_cast<float4*>(&wL[e][0])[k4] =
          reinterpret_cast<const float4*>(eW1 + (size_t)(e0 + e) * EMB)[k4];
    }
    __syncthreads();
    #pragma unroll 4
    for (int e = 0; e < 32; ++e) {
      float xs[4];
      #pragma unroll
      for (int rr = 0; rr < 4; ++rr) xs[rr] = xL[a * 4 + rr][e];
      const float4* wr = reinterpret_cast<const float4*>(&wL[e][0]) + b * 4;
      float wk[16];
      *reinterpret_cast<float4*>(&wk[0])  = wr[0];
      *reinterpret_cast<float4*>(&wk[4])  = wr[1];
      *reinterpret_cast<float4*>(&wk[8])  = wr[2];
      *reinterpret_cast<float4*>(&wk[12]) = wr[3];
      #pragma unroll
      for (int rr = 0; rr < 4; ++rr)
        #pragma unroll
        for (int kk = 0; kk < 16; ++kk)
          acc[rr][kk] = fmaf(xs[rr], wk[kk], acc[rr][kk]);
    }
    __syncthreads();
  }

  float eb2v = eb2[0];
  float pv[4];
  #pragma unroll
  for (int rr = 0; rr < 4; ++rr) {
    float s = 0.f;
    #pragma unroll
    for (int kk = 0; kk < 16; ++kk) {
      float h = acc[rr][kk] + eb1[b * 16 + kk];
      h = fmaxf(h, 0.f);
      s += h * eW2[b * 16 + kk];
    }
    pv[rr] = s;
  }
  #pragma unroll
  for (int m = 1; m < 16; m <<= 1) {
    #pragma unroll
    for (int rr = 0; rr < 4; ++rr) pv[rr] += __shfl_xor(pv[rr], m);
  }
  if (b == 0) {
    #pragma unroll
    for (int rr = 0; rr < 4; ++rr) val[m0 + a * 4 + rr] = pv[rr] + eb2v;
  }
}

__global__ void loss_kernel(const float* __restrict__ val, const float* __restrict__ pos,
                            const float* __restrict__ neg, const float* __restrict__ tgt,
                            const float* __restrict__ pwp, double* acc)
{
  const float pw = pwp[0];
  double l = 0.0, pk = 0.0, nk = 0.0;
  for (int m = blockIdx.x * blockDim.x + threadIdx.x; m < MM; m += gridDim.x * blockDim.x) {
    float v = val[m], p = pos[m], n = neg[m], t = tgt[m];
    float lp = log1pf(expf(-fabsf(v)));
    float spn = fmaxf(-v, 0.f) + lp;
    float spp = fmaxf(v, 0.f) + lp;
    float contrib = pw * t * spn + (1.f - t) * spp;
    l += (double)((p + n) * contrib);
    if (v >= 0.f) pk += (double)p; else nk += (double)n;
  }
  for (int o = 32; o; o >>= 1) {
    l += __shfl_down(l, o); pk += __shfl_down(pk, o); nk += __shfl_down(nk, o);
  }
  __shared__ double s0[4], s1[4], s2[4];
  int wid = threadIdx.x >> 6, lane = threadIdx.x & 63;
  if (lane == 0) { s0[wid] = l; s1[wid] = pk; s2[wid] = nk; }
  __syncthreads();
  if (threadIdx.x == 0) {
    double ta = 0.0, tb = 0.0, tc = 0.0;
    for (int w = 0; w < 4; ++w) { ta += s0[w]; tb += s1[w]; tc += s2[w]; }
    atomicAdd(&acc[2], ta); atomicAdd(&acc[3], tb); atomicAdd(&acc[4], tc);
  }
}

__global__ void writeout(const double* __restrict__ acc, float* __restrict__ out) {
  if (threadIdx.x == 0) {
    out[0] = (float)acc[2];
    out[1] = (float)acc[3];
    out[2] = (float)acc[4];
  }
}

extern "C" void kernel_launch(void* const* d_in, const int* in_sizes, int n_in,
                              void* d_out, int out_size, void* d_ws, size_t ws_size,
                              hipStream_t stream)
{
  (void)in_sizes; (void)n_in; (void)out_size; (void)ws_size;
  const float* init_vecs = (const float*)d_in[0];
  const float* W1  = (const float*)d_in[1];
  const float* b1  = (const float*)d_in[2];
  const float* W2  = (const float*)d_in[3];
  const float* b2  = (const float*)d_in[4];
  const float* eW1 = (const float*)d_in[5];
  const float* eb1 = (const float*)d_in[6];
  const float* eW2 = (const float*)d_in[7];
  const float* eb2 = (const float*)d_in[8];
  const float* pos = (const float*)d_in[9];
  const float* neg = (const float*)d_in[10];
  const float* tgt = (const float*)d_in[11];
  const int* inds  = (const int*)d_in[12];
  const int* pars  = (const int*)d_in[13];
  const int* rules = (const int*)d_in[14];
  const int* mask  = (const int*)d_in[15];

  char* ws = (char*)d_ws;
  float*    vec  = (float*)(ws + OFF_VEC);
  float*    hbuf = (float*)(ws + OFF_H);
  float*    val  = (float*)(ws + OFF_VAL);
  unsigned* cnt  = (unsigned*)(ws + OFF_CNT);
  double*   acc  = (double*)(ws + OFF_ACC);
  float*    pw   = (float*)(ws + OFF_PW);

  zero_scratch<<<1, 256, 0, stream>>>(cnt, acc);
  init_copy<<<256, 256, 0, stream>>>(init_vecs, vec);
  scan_kernel<<<256, 256, 0, stream>>>(W1, b1, W2, b2, inds, pars, rules, vec, hbuf, cnt);
  reduce_pn<<<128, 256, 0, stream>>>(pos, neg, acc);
  pw_kernel<<<1, 1, 0, stream>>>(acc, pw);
  eval_kernel<<<1024, 256, 0, stream>>>(vec, mask, eW1, eb1, eW2, eb2, val);
  loss_kernel<<<128, 256, 0, stream>>>(val, pos, neg, tgt, pw, acc);
  writeout<<<1, 1, 0, stream>>>(acc, (float*)d_out);
}

// Round 4
// 6295.838 us; speedup vs baseline: 4.4878x; 1.4983x over previous
//
#include <hip/hip_runtime.h>
#include <math.h>

#define EMB   256
#define TWOE  512
#define NINIT 1024
#define NSTEP 512
#define NPS   256
#define TOTAL (NINIT + NSTEP * NPS)   // 132096
#define MM    65536

// ---- workspace layout (bytes) ----
#define OFF_VEC 0
#define OFF_H   (TOTAL * EMB * 4)                  // 135266304
#define OFF_VAL (OFF_H + 2 * NPS * EMB * 4)        // hbuf double-buffered (512KB)
#define OFF_CNT (OFF_VAL + MM * 4)
#define OFF_FLG (OFF_CNT + 4096)                   // 512*16 u32 flags (32KB)
#define OFF_ACC (OFF_FLG + 32768)
#define OFF_PW  (OFF_ACC + 64)

// acc layout: [0]=sum(pos) [1]=sum(neg) [2]=loss [3]=posOK [4]=negOK

// ---- coherence-point (bypass L1/L2) ops ----
__device__ __forceinline__ void store_dev_f32(float* p, float v) {
  asm volatile("global_store_dword %0, %1, off sc0 sc1" :: "v"(p), "v"(v) : "memory");
}
__device__ __forceinline__ void store_dev_u32(unsigned* p, unsigned v) {
  asm volatile("global_store_dword %0, %1, off sc0 sc1" :: "v"(p), "v"(v) : "memory");
}
__device__ __forceinline__ unsigned load_dev_u32(const unsigned* p) {
  unsigned r;
  asm volatile("global_load_dword %0, %1, off sc0 sc1\n\ts_waitcnt vmcnt(0)"
               : "=v"(r) : "v"(p) : "memory");
  return r;
}
__device__ __forceinline__ float4 load_dev_f128(const float4* p) {
  float4 r;
  asm volatile("global_load_dwordx4 %0, %1, off sc0 sc1" : "=v"(r) : "v"(p));
  return r;
}

// 16-block group barrier (counter private to group, at coherence point)
__device__ __forceinline__ void gbar16(unsigned* c) {
  asm volatile("s_waitcnt vmcnt(0)" ::: "memory");  // drain our sc0sc1 stores
  __syncthreads();
  if (threadIdx.x == 0) {
    unsigned g = __hip_atomic_fetch_add(c, 1u, __ATOMIC_RELAXED, __HIP_MEMORY_SCOPE_AGENT);
    unsigned tgt = (g / 16u + 1u) * 16u;
    while (__hip_atomic_load(c, __ATOMIC_RELAXED, __HIP_MEMORY_SCOPE_AGENT) < tgt)
      __builtin_amdgcn_s_sleep(1);
  }
  __syncthreads();
}

// zeros cnt(4KB) + flags(32KB) + acc + pw : 9472 u32 from OFF_CNT
__global__ void zero_scratch(unsigned* base) {
  base[blockIdx.x * 256 + threadIdx.x] = 0u;
}

__global__ void init_copy(const float* __restrict__ src, float* __restrict__ dst) {
  int i = blockIdx.x * blockDim.x + threadIdx.x;
  reinterpret_cast<float4*>(dst)[i] = reinterpret_cast<const float4*>(src)[i];
}

// Persistent scan: 256 blocks x 256 threads; block (bi,bj) owns 16x16 out tile.
// Cross-step sync: per-(step, bi-group) done flags (point-to-point, no full barrier).
// Within step: one 16-way group barrier for the h exchange (hbuf parity-dbuf'd).
__global__ __launch_bounds__(256, 1)
void scan_kernel(const float* __restrict__ W1, const float* __restrict__ b1,
                 const float* __restrict__ W2, const float* __restrict__ b2,
                 const int* __restrict__ inds, const int* __restrict__ pars,
                 const int* __restrict__ rules,
                 float* __restrict__ vec, float* __restrict__ hbuf,
                 unsigned* __restrict__ cnt, unsigned* __restrict__ flags)
{
  __shared__ float pL[16][516];
  __shared__ float wT[16][516];
  __shared__ int spars[32];
  const int tid = threadIdx.x;
  const int bi = blockIdx.x >> 4;
  const int bj = blockIdx.x & 15;
  const int ti = tid >> 4;
  const int tj = tid & 15;
  const int c0 = bj * 16;
  unsigned* gc = cnt + 32 * bi;          // group barrier counter (128B apart)
  unsigned* pc = cnt + 512 + 32 * bi;    // publish arrival counter

  // ---- prologue: stage W1 tile for step 0 ----
  {
    const float* __restrict__ W1r = W1 + (size_t)rules[0] * TWOE * EMB;
    for (int idx = tid; idx < TWOE * 4; idx += 256) {
      int k = idx >> 2, cq = idx & 3;
      float4 w = *reinterpret_cast<const float4*>(W1r + (size_t)k * EMB + c0 + cq * 4);
      wT[cq * 4 + 0][k] = w.x; wT[cq * 4 + 1][k] = w.y;
      wT[cq * 4 + 2][k] = w.z; wT[cq * 4 + 3][k] = w.w;
    }
  }

  for (int s = 0;;) {
    const int r = rules[s];
    // ---- flag-guarded parent index load (wave 0, lanes 0..31) ----
    if (tid < 32) {
      int p = pars[(size_t)s * 512 + bi * 32 + tid];
      spars[tid] = p;
      if (p >= NINIT) {
        int pr = p - NINIT;
        const unsigned* f = flags + (pr >> 8) * 16 + ((pr & 255) >> 4);
        while (load_dev_u32(f) == 0u) __builtin_amdgcn_s_sleep(1);
      }
    }
    __syncthreads();
    // ---- gather 16 rows x 512 floats (normal cached: rows write-once) ----
    for (int idx = tid; idx < 16 * 128; idx += 256) {
      int row = idx >> 7, c4 = idx & 127;
      int par = spars[row * 2 + (c4 >> 6)];
      float4 v = reinterpret_cast<const float4*>(vec + (size_t)par * EMB)[c4 & 63];
      reinterpret_cast<float4*>(&pL[row][0])[c4] = v;
    }
    __syncthreads();
    // ---- phase 1: h tile -> hbuf (parity s&1), coherent store ----
    {
      const float4* p4 = reinterpret_cast<const float4*>(&pL[ti][0]);
      const float4* w4 = reinterpret_cast<const float4*>(&wT[tj][0]);
      float sx = 0.f, sy = 0.f, sz = 0.f, sw = 0.f;
      #pragma unroll 8
      for (int k4 = 0; k4 < TWOE / 4; ++k4) {
        float4 a = p4[k4], w = w4[k4];
        sx += a.x * w.x; sy += a.y * w.y; sz += a.z * w.z; sw += a.w * w.w;
      }
      float h = b1[r * EMB + c0 + tj] + ((sx + sy) + (sz + sw));
      store_dev_f32(hbuf + (size_t)((s & 1) * NPS + bi * 16 + ti) * EMB + c0 + tj,
                    fmaxf(h, 0.f));
    }
    __syncthreads();                    // wT (W1) reads complete
    // ---- stage W2 tile now (off critical path: before the group barrier) ----
    {
      const float* __restrict__ W2r = W2 + (size_t)r * EMB * EMB;
      for (int idx = tid; idx < EMB * 4; idx += 256) {
        int k = idx >> 2, cq = idx & 3;
        float4 w = *reinterpret_cast<const float4*>(W2r + (size_t)k * EMB + c0 + cq * 4);
        wT[cq * 4 + 0][k] = w.x; wT[cq * 4 + 1][k] = w.y;
        wT[cq * 4 + 2][k] = w.z; wT[cq * 4 + 3][k] = w.w;
      }
    }
    gbar16(gc);                         // h tiles of this group all visible
    // ---- load h rows (coherent), into pL ----
    {
      const int i0 = tid, i1 = tid + 256, i2 = tid + 512, i3 = tid + 768;
      const float4* hb = reinterpret_cast<const float4*>(
          hbuf + (size_t)((s & 1) * NPS + bi * 16) * EMB);
      float4 h0 = load_dev_f128(hb + i0);
      float4 h1 = load_dev_f128(hb + i1);
      float4 h2 = load_dev_f128(hb + i2);
      float4 h3 = load_dev_f128(hb + i3);
      asm volatile("s_waitcnt vmcnt(0)" ::: "memory");
      __builtin_amdgcn_sched_barrier(0);
      reinterpret_cast<float4*>(&pL[i0 >> 6][0])[i0 & 63] = h0;
      reinterpret_cast<float4*>(&pL[i1 >> 6][0])[i1 & 63] = h1;
      reinterpret_cast<float4*>(&pL[i2 >> 6][0])[i2 & 63] = h2;
      reinterpret_cast<float4*>(&pL[i3 >> 6][0])[i3 & 63] = h3;
    }
    __syncthreads();
    // ---- phase 2: out tile -> vec (coherent scatter) ----
    {
      const float4* p4 = reinterpret_cast<const float4*>(&pL[ti][0]);
      const float4* w4 = reinterpret_cast<const float4*>(&wT[tj][0]);
      float sx = 0.f, sy = 0.f, sz = 0.f, sw = 0.f;
      #pragma unroll 8
      for (int k4 = 0; k4 < EMB / 4; ++k4) {
        float4 a = p4[k4], w = w4[k4];
        sx += a.x * w.x; sy += a.y * w.y; sz += a.z * w.z; sw += a.w * w.w;
      }
      float o = b2[r * EMB + c0 + tj] + ((sx + sy) + (sz + sw));
      int orow = inds[s * NPS + bi * 16 + ti];
      store_dev_f32(vec + (size_t)orow * EMB + c0 + tj, o);
    }
    // ---- publish: last-arriving block of group sets flag[s][bi] ----
    asm volatile("s_waitcnt vmcnt(0)" ::: "memory");
    __syncthreads();                    // all waves' scatters drained; wT/pL free
    if (tid == 255) {                   // wave 3: wave 0 can start next flag check
      unsigned old = __hip_atomic_fetch_add(pc, 1u, __ATOMIC_RELAXED,
                                            __HIP_MEMORY_SCOPE_AGENT);
      if ((old & 15u) == 15u) store_dev_u32(flags + s * 16 + bi, 1u);
    }
    ++s;
    if (s == NSTEP) break;
    // ---- stage next W1 tile (overlaps next flag spin / publish) ----
    {
      const float* __restrict__ W1n = W1 + (size_t)rules[s] * TWOE * EMB;
      for (int idx = tid; idx < TWOE * 4; idx += 256) {
        int k = idx >> 2, cq = idx & 3;
        float4 w = *reinterpret_cast<const float4*>(W1n + (size_t)k * EMB + c0 + cq * 4);
        wT[cq * 4 + 0][k] = w.x; wT[cq * 4 + 1][k] = w.y;
        wT[cq * 4 + 2][k] = w.z; wT[cq * 4 + 3][k] = w.w;
      }
    }
  }
}

__global__ void reduce_pn(const float* __restrict__ pos, const float* __restrict__ neg,
                          double* acc) {
  double sp = 0.0, sn = 0.0;
  for (int m = blockIdx.x * blockDim.x + threadIdx.x; m < MM; m += gridDim.x * blockDim.x) {
    sp += (double)pos[m]; sn += (double)neg[m];
  }
  for (int o = 32; o; o >>= 1) { sp += __shfl_down(sp, o); sn += __shfl_down(sn, o); }
  __shared__ double rp[4], rn[4];
  int wid = threadIdx.x >> 6, lane = threadIdx.x & 63;
  if (lane == 0) { rp[wid] = sp; rn[wid] = sn; }
  __syncthreads();
  if (threadIdx.x == 0) {
    double tp = 0.0, tn = 0.0;
    for (int w = 0; w < 4; ++w) { tp += rp[w]; tn += rn[w]; }
    atomicAdd(&acc[0], tp); atomicAdd(&acc[1], tn);
  }
}

__global__ void pw_kernel(const double* __restrict__ acc, float* __restrict__ pw) {
  pw[0] = (float)(acc[1] / fmax(acc[0], 1.0));
}

__global__ __launch_bounds__(256)
void eval_kernel(const float* __restrict__ vec, const int* __restrict__ mask,
                 const float* __restrict__ eW1, const float* __restrict__ eb1,
                 const float* __restrict__ eW2, const float* __restrict__ eb2,
                 float* __restrict__ val)
{
  __shared__ float xL[64][36];
  __shared__ float wL[32][260];
  __shared__ int mrow[64];
  const int tid = threadIdx.x;
  const int a = tid >> 4, b = tid & 15;
  const int m0 = blockIdx.x * 64;
  if (tid < 64) mrow[tid] = mask[m0 + tid];
  __syncthreads();

  float acc[4][16];
  #pragma unroll
  for (int i = 0; i < 4; ++i)
    #pragma unroll
    for (int j = 0; j < 16; ++j) acc[i][j] = 0.f;

  for (int c = 0; c < 8; ++c) {
    const int e0 = c * 32;
    for (int idx = tid; idx < 64 * 8; idx += 256) {
      int rr = idx >> 3, e4 = idx & 7;
      float4 v = reinterpret_cast<const float4*>(vec + (size_t)mrow[rr] * EMB + e0)[e4];
      reinterpret_cast<float4*>(&xL[rr][0])[e4] = v;
    }
    for (int idx = tid; idx < 32 * 64; idx += 256) {
      int e = idx >> 6, k4 = idx & 63;
      reinterpret_cast<float4*>(&wL[e][0])[k4] =
          reinterpret_cast<const float4*>(eW1 + (size_t)(e0 + e) * EMB)[k4];
    }
    __syncthreads();
    #pragma unroll 4
    for (int e = 0; e < 32; ++e) {
      float xs[4];
      #pragma unroll
      for (int rr = 0; rr < 4; ++rr) xs[rr] = xL[a * 4 + rr][e];
      const float4* wr = reinterpret_cast<const float4*>(&wL[e][0]) + b * 4;
      float wk[16];
      *reinterpret_cast<float4*>(&wk[0])  = wr[0];
      *reinterpret_cast<float4*>(&wk[4])  = wr[1];
      *reinterpret_cast<float4*>(&wk[8])  = wr[2];
      *reinterpret_cast<float4*>(&wk[12]) = wr[3];
      #pragma unroll
      for (int rr = 0; rr < 4; ++rr)
        #pragma unroll
        for (int kk = 0; kk < 16; ++kk)
          acc[rr][kk] = fmaf(xs[rr], wk[kk], acc[rr][kk]);
    }
    __syncthreads();
  }

  float eb2v = eb2[0];
  float pv[4];
  #pragma unroll
  for (int rr = 0; rr < 4; ++rr) {
    float s = 0.f;
    #pragma unroll
    for (int kk = 0; kk < 16; ++kk) {
      float h = acc[rr][kk] + eb1[b * 16 + kk];
      h = fmaxf(h, 0.f);
      s += h * eW2[b * 16 + kk];
    }
    pv[rr] = s;
  }
  #pragma unroll
  for (int m = 1; m < 16; m <<= 1) {
    #pragma unroll
    for (int rr = 0; rr < 4; ++rr) pv[rr] += __shfl_xor(pv[rr], m);
  }
  if (b == 0) {
    #pragma unroll
    for (int rr = 0; rr < 4; ++rr) val[m0 + a * 4 + rr] = pv[rr] + eb2v;
  }
}

__global__ void loss_kernel(const float* __restrict__ val, const float* __restrict__ pos,
                            const float* __restrict__ neg, const float* __restrict__ tgt,
                            const float* __restrict__ pwp, double* acc)
{
  const float pw = pwp[0];
  double l = 0.0, pk = 0.0, nk = 0.0;
  for (int m = blockIdx.x * blockDim.x + threadIdx.x; m < MM; m += gridDim.x * blockDim.x) {
    float v = val[m], p = pos[m], n = neg[m], t = tgt[m];
    float lp = log1pf(expf(-fabsf(v)));
    float spn = fmaxf(-v, 0.f) + lp;
    float spp = fmaxf(v, 0.f) + lp;
    float contrib = pw * t * spn + (1.f - t) * spp;
    l += (double)((p + n) * contrib);
    if (v >= 0.f) pk += (double)p; else nk += (double)n;
  }
  for (int o = 32; o; o >>= 1) {
    l += __shfl_down(l, o); pk += __shfl_down(pk, o); nk += __shfl_down(nk, o);
  }
  __shared__ double s0[4], s1[4], s2[4];
  int wid = threadIdx.x >> 6, lane = threadIdx.x & 63;
  if (lane == 0) { s0[wid] = l; s1[wid] = pk; s2[wid] = nk; }
  __syncthreads();
  if (threadIdx.x == 0) {
    double ta = 0.0, tb = 0.0, tc = 0.0;
    for (int w = 0; w < 4; ++w) { ta += s0[w]; tb += s1[w]; tc += s2[w]; }
    atomicAdd(&acc[2], ta); atomicAdd(&acc[3], tb); atomicAdd(&acc[4], tc);
  }
}

__global__ void writeout(const double* __restrict__ acc, float* __restrict__ out) {
  if (threadIdx.x == 0) {
    out[0] = (float)acc[2];
    out[1] = (float)acc[3];
    out[2] = (float)acc[4];
  }
}

extern "C" void kernel_launch(void* const* d_in, const int* in_sizes, int n_in,
                              void* d_out, int out_size, void* d_ws, size_t ws_size,
                              hipStream_t stream)
{
  (void)in_sizes; (void)n_in; (void)out_size; (void)ws_size;
  const float* init_vecs = (const float*)d_in[0];
  const float* W1  = (const float*)d_in[1];
  const float* b1  = (const float*)d_in[2];
  const float* W2  = (const float*)d_in[3];
  const float* b2  = (const float*)d_in[4];
  const float* eW1 = (const float*)d_in[5];
  const float* eb1 = (const float*)d_in[6];
  const float* eW2 = (const float*)d_in[7];
  const float* eb2 = (const float*)d_in[8];
  const float* pos = (const float*)d_in[9];
  const float* neg = (const float*)d_in[10];
  const float* tgt = (const float*)d_in[11];
  const int* inds  = (const int*)d_in[12];
  const int* pars  = (const int*)d_in[13];
  const int* rules = (const int*)d_in[14];
  const int* mask  = (const int*)d_in[15];

  char* ws = (char*)d_ws;
  float*    vec  = (float*)(ws + OFF_VEC);
  float*    hbuf = (float*)(ws + OFF_H);
  float*    val  = (float*)(ws + OFF_VAL);
  unsigned* cnt  = (unsigned*)(ws + OFF_CNT);
  unsigned* flg  = (unsigned*)(ws + OFF_FLG);
  double*   acc  = (double*)(ws + OFF_ACC);
  float*    pw   = (float*)(ws + OFF_PW);

  zero_scratch<<<37, 256, 0, stream>>>(cnt);   // cnt + flags + acc + pw
  init_copy<<<256, 256, 0, stream>>>(init_vecs, vec);
  scan_kernel<<<256, 256, 0, stream>>>(W1, b1, W2, b2, inds, pars, rules,
                                       vec, hbuf, cnt, flg);
  reduce_pn<<<128, 256, 0, stream>>>(pos, neg, acc);
  pw_kernel<<<1, 1, 0, stream>>>(acc, pw);
  eval_kernel<<<1024, 256, 0, stream>>>(vec, mask, eW1, eb1, eW2, eb2, val);
  loss_kernel<<<128, 256, 0, stream>>>(val, pos, neg, tgt, pw, acc);
  writeout<<<1, 1, 0, stream>>>(acc, (float*)d_out);
}